// Round 5
// baseline (240.205 us; speedup 1.0000x reference)
//
#include <hip/hip_runtime.h>
#include <hip/hip_bf16.h>

// ---------------------------------------------------------------------------
// CrossAttention on MI355X (gfx950) — v5: bank-conflict-free (XOR-swizzled)
// GEMM LDS, 128x128 merged QK GEMM (3 blk/CU), 128x64 O-proj.
// ---------------------------------------------------------------------------

typedef unsigned short u16;
typedef __bf16 bf16x8 __attribute__((ext_vector_type(8)));
typedef float f32x4 __attribute__((ext_vector_type(4)));

__device__ inline f32x4 mfma16(bf16x8 a, bf16x8 b, f32x4 c) {
    return __builtin_amdgcn_mfma_f32_16x16x32_bf16(a, b, c, 0, 0, 0);
}

__device__ inline u16 f2bf(float f) {
    union { float f; unsigned u; } v; v.f = f;
    unsigned r = v.u + 0x7fffu + ((v.u >> 16) & 1u);
    return (u16)(r >> 16);
}

__device__ inline float bf2f(u16 x) {
    union { unsigned u; float f; } v; v.u = ((unsigned)x) << 16; return v.f;
}

// pack two f32 -> two bf16 in one u32 (round: add 0x8000 + v_perm)
__device__ inline unsigned pk_bf16(float a, float b) {
    union { float f; unsigned u; } x, y; x.f = a; y.f = b;
    return __builtin_amdgcn_perm(y.u + 0x8000u, x.u + 0x8000u, 0x07060302u);
}

__device__ inline void load_lds16(const void* g, void* l) {
    __builtin_amdgcn_global_load_lds(
        (const __attribute__((address_space(1))) void*)g,
        (__attribute__((address_space(3))) void*)l, 16, 0, 0);
}

// ---------------------------------------------------------------------------
// fused cast: text (1048576 f4) + Wq + Wk + Wo (262144 f4 each)
__global__ __launch_bounds__(256) void cast4_kernel(const float* __restrict__ text,
                                                    const float* __restrict__ Wq,
                                                    const float* __restrict__ Wk,
                                                    const float* __restrict__ Wo,
                                                    u16* __restrict__ otext, u16* __restrict__ oWq,
                                                    u16* __restrict__ oWk, u16* __restrict__ oWo) {
    int i = blockIdx.x * 256 + threadIdx.x;
    const float* src; u16* dst; int off;
    if (i < 1048576)      { src = text; dst = otext; off = i; }
    else if (i < 1310720) { src = Wq;   dst = oWq;   off = i - 1048576; }
    else if (i < 1572864) { src = Wk;   dst = oWk;   off = i - 1310720; }
    else                  { src = Wo;   dst = oWo;   off = i - 1572864; }
    float4 v = ((const float4*)src)[off];
    uint2 p; p.x = pk_bf16(v.x, v.y); p.y = pk_bf16(v.z, v.w);
    ((uint2*)dst)[off] = p;
}

// ---------------------------------------------------------------------------
// RMSNorm (last dim 1024), fp32 in, bf16 out, constant output scale.
__global__ __launch_bounds__(256) void rmsnorm_kernel(const float* __restrict__ in,
                                                      const float* __restrict__ g,
                                                      u16* __restrict__ out, float scale) {
    int row = blockIdx.x, tid = threadIdx.x;
    float4 v = ((const float4*)(in + (size_t)row * 1024))[tid];
    float ss = v.x * v.x + v.y * v.y + v.z * v.z + v.w * v.w;
    #pragma unroll
    for (int m = 1; m < 64; m <<= 1) ss += __shfl_xor(ss, m, 64);
    __shared__ float ws[4];
    if ((tid & 63) == 0) ws[tid >> 6] = ss;
    __syncthreads();
    float rs = rsqrtf((ws[0] + ws[1] + ws[2] + ws[3]) * (1.0f / 1024.0f) + 1e-6f) * scale;
    float4 gv = ((const float4*)g)[tid];
    uint2 p;
    p.x = pk_bf16(v.x * rs * gv.x, v.y * rs * gv.y);
    p.y = pk_bf16(v.z * rs * gv.z, v.w * rs * gv.w);
    ((uint2*)(out + (size_t)row * 1024))[tid] = p;
}

// ---------------------------------------------------------------------------
// In-place RMSNorm on bf16 rows: rows 0..4095 = Q (g_q, qscale), 4096.. = K (g_k).
__global__ __launch_bounds__(256) void rmsnorm_qk_kernel(u16* __restrict__ QK,
                                                         const float* __restrict__ g_q,
                                                         const float* __restrict__ g_k,
                                                         float qscale) {
    int row = blockIdx.x, tid = threadIdx.x;
    const float* g = (row < 4096) ? g_q : g_k;
    float outsc = (row < 4096) ? qscale : 1.0f;
    uint2* rp = (uint2*)(QK + (size_t)row * 1024) + tid;
    union { u16 s[4]; uint2 v; } in; in.v = *rp;
    float x0 = bf2f(in.s[0]), x1 = bf2f(in.s[1]), x2 = bf2f(in.s[2]), x3 = bf2f(in.s[3]);
    float ss = x0 * x0 + x1 * x1 + x2 * x2 + x3 * x3;
    #pragma unroll
    for (int m = 1; m < 64; m <<= 1) ss += __shfl_xor(ss, m, 64);
    __shared__ float ws[4];
    if ((tid & 63) == 0) ws[tid >> 6] = ss;
    __syncthreads();
    float rs = rsqrtf((ws[0] + ws[1] + ws[2] + ws[3]) * (1.0f / 1024.0f) + 1e-6f) * outsc;
    float4 gv = ((const float4*)g)[tid];
    uint2 p;
    p.x = pk_bf16(x0 * rs * gv.x, x1 * rs * gv.y);
    p.y = pk_bf16(x2 * rs * gv.z, x3 * rs * gv.w);
    *rp = p;
}

// ---------------------------------------------------------------------------
__global__ __launch_bounds__(256) void transpose_kernel(const u16* __restrict__ in,
                                                        u16* __restrict__ out) {
    __shared__ __align__(16) u16 tile[64][72];
    int tid = threadIdx.x, b = blockIdx.z;
    int n0 = blockIdx.x * 64, d0 = blockIdx.y * 64;
    int r = tid >> 2, cs = (tid & 3) * 16;
    const u16* src = in + ((size_t)(b * 1024 + n0 + r)) * 1024 + d0 + cs;
    union { u16 s[8]; uint4 v; } a0, a1;
    a0.v = *(const uint4*)src;
    a1.v = *(const uint4*)(src + 8);
    #pragma unroll
    for (int i = 0; i < 8; ++i) { tile[r][cs + i] = a0.s[i]; tile[r][cs + 8 + i] = a1.s[i]; }
    __syncthreads();
    union { u16 s[8]; uint4 v; } b0, b1;
    #pragma unroll
    for (int i = 0; i < 8; ++i) { b0.s[i] = tile[cs + i][r]; b1.s[i] = tile[cs + 8 + i][r]; }
    u16* dst = out + ((size_t)(b * 1024 + d0 + r)) * 1024 + n0 + cs;
    *(uint4*)dst = b0.v;
    *(uint4*)(dst + 8) = b1.v;
}

// ---------------------------------------------------------------------------
// 128x128-tile GEMM body, XOR-swizzled LDS (chunk c of row r stored at
// position c ^ ((r>>1)&3) -> fragment ds_read_b128 is 2-way max = free).
template <bool BF16OUT>
__device__ __forceinline__ void gemm128_tile(const u16* __restrict__ A, const u16* __restrict__ B,
                                             const float* __restrict__ bias, void* __restrict__ Cout,
                                             int m_blk, int n_blk, int K, int N,
                                             u16* As, u16* Bs) {
    int tid = threadIdx.x, wave = tid >> 6, lane = tid & 63;
    int quad = lane >> 4, l15 = lane & 15;
    int wm = wave & 1, wn = wave >> 1;
    int sw = (l15 >> 1) & 3;

    f32x4 acc[4][4] = {};

    for (int k0 = 0; k0 < K; k0 += 32) {
        #pragma unroll
        for (int j = 0; j < 2; ++j) {
            int idx = j * 256 + tid;
            int row = idx >> 2;
            int c = ((idx & 3) ^ ((idx >> 3) & 3)) * 8;   // swizzled source chunk
            load_lds16(A + (size_t)(m_blk + row) * K + k0 + c, As + (j * 256 + wave * 64) * 8);
            load_lds16(B + (size_t)(n_blk + row) * K + k0 + c, Bs + (j * 256 + wave * 64) * 8);
        }
        __syncthreads();
        bf16x8 af[4], bfr[4];
        #pragma unroll
        for (int t = 0; t < 4; ++t) {
            af[t]  = *(const bf16x8*)&As[(wm * 64 + t * 16 + l15) * 32 + (quad ^ sw) * 8];
            bfr[t] = *(const bf16x8*)&Bs[(wn * 64 + t * 16 + l15) * 32 + (quad ^ sw) * 8];
        }
        #pragma unroll
        for (int mt = 0; mt < 4; ++mt)
            #pragma unroll
            for (int nt = 0; nt < 4; ++nt)
                acc[mt][nt] = mfma16(af[mt], bfr[nt], acc[mt][nt]);
        __syncthreads();
    }
    #pragma unroll
    for (int nt = 0; nt < 4; ++nt) {
        int col = n_blk + wn * 64 + nt * 16 + l15;
        float bv = bias[col];
        #pragma unroll
        for (int mt = 0; mt < 4; ++mt) {
            int row0 = m_blk + wm * 64 + mt * 16 + quad * 4;
            #pragma unroll
            for (int r = 0; r < 4; ++r) {
                float val = acc[mt][nt][r] + bv;
                if (BF16OUT) ((u16*)Cout)[(size_t)(row0 + r) * N + col] = f2bf(val);
                else       ((float*)Cout)[(size_t)(row0 + r) * N + col] = val;
            }
        }
    }
}

// 128x64-tile variant (for O-proj: 512 blocks -> 2 blk/CU), swizzled LDS.
template <bool BF16OUT>
__device__ __forceinline__ void gemm64_tile(const u16* __restrict__ A, const u16* __restrict__ B,
                                            const float* __restrict__ bias, void* __restrict__ Cout,
                                            int m_blk, int n_blk, int K, int N,
                                            u16* As, u16* Bs) {
    int tid = threadIdx.x, wave = tid >> 6, lane = tid & 63;
    int quad = lane >> 4, l15 = lane & 15;
    int wm = wave & 1, wn = wave >> 1;
    int sw = (l15 >> 1) & 3;

    f32x4 acc[4][2] = {};

    for (int k0 = 0; k0 < K; k0 += 32) {
        #pragma unroll
        for (int j = 0; j < 2; ++j) {
            int idx = j * 256 + tid;
            int row = idx >> 2;
            int c = ((idx & 3) ^ ((idx >> 3) & 3)) * 8;
            load_lds16(A + (size_t)(m_blk + row) * K + k0 + c, As + (j * 256 + wave * 64) * 8);
        }
        {
            int row = tid >> 2;
            int c = ((tid & 3) ^ ((tid >> 3) & 3)) * 8;
            load_lds16(B + (size_t)(n_blk + row) * K + k0 + c, Bs + (wave * 64) * 8);
        }
        __syncthreads();
        bf16x8 af[4], bfr[2];
        #pragma unroll
        for (int t = 0; t < 4; ++t)
            af[t] = *(const bf16x8*)&As[(wm * 64 + t * 16 + l15) * 32 + (quad ^ sw) * 8];
        #pragma unroll
        for (int t = 0; t < 2; ++t)
            bfr[t] = *(const bf16x8*)&Bs[(wn * 32 + t * 16 + l15) * 32 + (quad ^ sw) * 8];
        #pragma unroll
        for (int mt = 0; mt < 4; ++mt)
            #pragma unroll
            for (int nt = 0; nt < 2; ++nt)
                acc[mt][nt] = mfma16(af[mt], bfr[nt], acc[mt][nt]);
        __syncthreads();
    }
    #pragma unroll
    for (int nt = 0; nt < 2; ++nt) {
        int col = n_blk + wn * 32 + nt * 16 + l15;
        float bv = bias[col];
        #pragma unroll
        for (int mt = 0; mt < 4; ++mt) {
            int row0 = m_blk + wm * 64 + mt * 16 + quad * 4;
            #pragma unroll
            for (int r = 0; r < 4; ++r) {
                float val = acc[mt][nt][r] + bv;
                if (BF16OUT) ((u16*)Cout)[(size_t)(row0 + r) * N + col] = f2bf(val);
                else       ((float*)Cout)[(size_t)(row0 + r) * N + col] = val;
            }
        }
    }
}

// merged Q-proj (256 blocks) + K-proj (512 blocks), 128x128 tiles, bf16 out
__global__ __launch_bounds__(256) void gemm_qk_kernel(const u16* __restrict__ text_bf,
                                                      const u16* __restrict__ Wq,
                                                      const u16* __restrict__ feats_bf,
                                                      const u16* __restrict__ Wk,
                                                      const float* __restrict__ b_q,
                                                      const float* __restrict__ b_k,
                                                      u16* __restrict__ QK) {
    __shared__ __align__(16) u16 As[128 * 32];
    __shared__ __align__(16) u16 Bs[128 * 32];
    int id = blockIdx.x;
    if (id < 256) {
        gemm128_tile<true>(text_bf, Wq, b_q, QK, (id & 31) * 128, (id >> 5) * 128, 1024, 1024, As, Bs);
    } else {
        id -= 256;
        gemm128_tile<true>(feats_bf, Wk, b_k, QK + 4096 * 1024,
                           (id & 63) * 128, (id >> 6) * 128, 1024, 1024, As, Bs);
    }
}

// O-projection, fp32 out, 128x64 tiles (512 blocks)
__global__ __launch_bounds__(256) void gemm_o_kernel(const u16* __restrict__ A,
                                                     const u16* __restrict__ B,
                                                     const float* __restrict__ bias,
                                                     float* __restrict__ C) {
    __shared__ __align__(16) u16 As[128 * 32];
    __shared__ __align__(16) u16 Bs[64 * 32];
    int id = blockIdx.x;
    gemm64_tile<false>(A, B, bias, C, (id & 31) * 128, (id >> 5) * 64, 1024, 1024, As, Bs);
}

// ---------------------------------------------------------------------------
// Flash attention (v4 structure): n-chunk 64, 25.6KB LDS, fixed-max exp2
// softmax, S^T/O^T MFMA orientation, XOR-swizzled K/V staging.
__global__ __launch_bounds__(256) void attn_kernel(const u16* __restrict__ Q,
                                                   const u16* __restrict__ K,
                                                   const u16* __restrict__ Vt,
                                                   u16* __restrict__ Out) {
    int bh = blockIdx.x, qt = blockIdx.y;
    int b = bh >> 4, h = bh & 15;
    int tid = threadIdx.x, wave = tid >> 6, lane = tid & 63;
    int quad = lane >> 4, l15 = lane & 15;

    __shared__ __align__(16) u16 Ks[64 * 64];
    __shared__ __align__(16) u16 Vs[64 * 64];
    __shared__ __align__(16) u16 Plds[4][16 * 72];
    u16* Pw = &Plds[wave][0];

    const size_t qoff = ((size_t)(b * 512 + qt * 64 + wave * 16 + l15)) * 1024 + h * 64 + quad * 8;
    bf16x8 qf0 = *(const bf16x8*)(Q + qoff);
    bf16x8 qf1 = *(const bf16x8*)(Q + qoff + 32);

    int srl = lane >> 3, scl = lane & 7;
    const u16* Kbase = K + ((size_t)(b * 1024)) * 1024 + h * 64;
    const u16* Vbase = Vt + ((size_t)(b * 1024 + h * 64)) * 1024;

    __bf16 onev = (__bf16)1.0f;
    bf16x8 ones = {onev, onev, onev, onev, onev, onev, onev, onev};

    f32x4 o[4] = {};
    f32x4 lac = {0.0f, 0.0f, 0.0f, 0.0f};

    for (int n0 = 0; n0 < 1024; n0 += 64) {
        #pragma unroll
        for (int j = 0; j < 2; ++j) {
            int row = wave * 16 + j * 8 + srl;
            load_lds16(Kbase + (size_t)(n0 + row) * 1024 + (scl ^ srl) * 8,
                       Ks + (wave * 16 + j * 8) * 64);
            load_lds16(Vbase + (size_t)row * 1024 + n0 + (scl ^ srl) * 8,
                       Vs + (wave * 16 + j * 8) * 64);
        }
        __syncthreads();

        f32x4 s[4];
        #pragma unroll
        for (int nt = 0; nt < 4; ++nt) {
            int R = nt * 16 + l15;
            int c1 = (quad ^ (l15 & 7)) * 8;
            bf16x8 kf0 = *(const bf16x8*)&Ks[R * 64 + c1];
            bf16x8 kf1 = *(const bf16x8*)&Ks[R * 64 + (c1 ^ 32)];
            f32x4 z = {-16.0f, -16.0f, -16.0f, -16.0f};
            s[nt] = mfma16(kf0, qf0, z);
            s[nt] = mfma16(kf1, qf1, s[nt]);
        }

        #pragma unroll
        for (int nt = 0; nt < 4; ++nt) {
            uint2 pk;
            pk.x = pk_bf16(exp2f(s[nt][0]), exp2f(s[nt][1]));
            pk.y = pk_bf16(exp2f(s[nt][2]), exp2f(s[nt][3]));
            *(uint2*)&Pw[l15 * 72 + nt * 16 + quad * 4] = pk;
        }

        bf16x8 pf[2];
        #pragma unroll
        for (int kc = 0; kc < 2; ++kc)
            pf[kc] = *(const bf16x8*)&Pw[l15 * 72 + kc * 32 + quad * 8];
        #pragma unroll
        for (int kc = 0; kc < 2; ++kc) {
            lac = mfma16(ones, pf[kc], lac);
            #pragma unroll
            for (int dt = 0; dt < 4; ++dt) {
                int d = dt * 16 + l15;
                int ch = ((kc * 4 + quad) ^ (l15 & 7)) * 8;
                bf16x8 vf = *(const bf16x8*)&Vs[d * 64 + ch];
                o[dt] = mfma16(vf, pf[kc], o[dt]);
            }
        }
        __syncthreads();
    }

    float il = 1.0f / lac[0];
    size_t obase = ((size_t)(b * 512 + qt * 64 + wave * 16 + l15)) * 1024 + h * 64 + quad * 4;
    #pragma unroll
    for (int dt = 0; dt < 4; ++dt) {
        uint2 pk;
        pk.x = pk_bf16(o[dt][0] * il, o[dt][1] * il);
        pk.y = pk_bf16(o[dt][2] * il, o[dt][3] * il);
        *(uint2*)(Out + obase + dt * 16) = pk;
    }
}

// ---------------------------------------------------------------------------
extern "C" void kernel_launch(void* const* d_in, const int* in_sizes, int n_in,
                              void* d_out, int out_size, void* d_ws, size_t ws_size,
                              hipStream_t stream) {
    const float* text     = (const float*)d_in[0];
    const float* features = (const float*)d_in[1];
    const float* W_q      = (const float*)d_in[2];
    const float* b_q      = (const float*)d_in[3];
    const float* W_k      = (const float*)d_in[4];
    const float* b_k      = (const float*)d_in[5];
    const float* W_o      = (const float*)d_in[6];
    const float* b_o      = (const float*)d_in[7];
    const float* g_feat   = (const float*)d_in[8];
    const float* g_q      = (const float*)d_in[9];
    const float* g_k      = (const float*)d_in[10];

    char* ws = (char*)d_ws;
    u16* text_bf  = (u16*)(ws + 0);            //  8 MB [4096,1024]
    u16* Wq_bf    = (u16*)(ws + 8388608);      //  2 MB
    u16* Wk_bf    = (u16*)(ws + 10485760);     //  2 MB
    u16* Wo_bf    = (u16*)(ws + 12582912);     //  2 MB
    u16* feats_bf = (u16*)(ws + 14680064);     // 16 MB [8192,1024]
    u16* Vt       = (u16*)(ws + 31457280);     // 16 MB [8][1024 d][1024 n]
    u16* QKbuf    = (u16*)(ws + 48234496);     // 24 MB [12288,1024] (Q, then K)
    u16* attn_bf  = (u16*)(ws + 73400320);     //  8 MB [4096,1024]

    const float QSCALE = 0.18033688011112042f; // 0.125 * log2(e)

    cast4_kernel<<<7168, 256, 0, stream>>>(text, W_q, W_k, W_o, text_bf, Wq_bf, Wk_bf, Wo_bf);

    rmsnorm_kernel<<<8192, 256, 0, stream>>>(features, g_feat, feats_bf, 1.0f);
    transpose_kernel<<<dim3(16, 16, 8), 256, 0, stream>>>(feats_bf, Vt);

    gemm_qk_kernel<<<768, 256, 0, stream>>>(text_bf, Wq_bf, feats_bf, Wk_bf, b_q, b_k, QKbuf);
    rmsnorm_qk_kernel<<<12288, 256, 0, stream>>>(QKbuf, g_q, g_k, QSCALE);

    attn_kernel<<<dim3(128, 8), 256, 0, stream>>>(QKbuf, QKbuf + 4096 * 1024, Vt, attn_bf);

    gemm_o_kernel<<<512, 256, 0, stream>>>(attn_bf, Wo_bf, b_o, (float*)d_out);
}

// Round 6
// 225.032 us; speedup vs baseline: 1.0674x; 1.0674x over previous
//
#include <hip/hip_runtime.h>
#include <hip/hip_bf16.h>

// ---------------------------------------------------------------------------
// CrossAttention on MI355X (gfx950) — v6: v4 GEMM layout + BK=64 (half the
// barrier drains, split-half LDS keeps 64B row stride), fused cast+rowss,
// fused normalize+transpose (normT), wave-per-row rmsnorm_qk. 6 launches.
// ---------------------------------------------------------------------------

typedef unsigned short u16;
typedef __bf16 bf16x8 __attribute__((ext_vector_type(8)));
typedef float f32x4 __attribute__((ext_vector_type(4)));

__device__ inline f32x4 mfma16(bf16x8 a, bf16x8 b, f32x4 c) {
    return __builtin_amdgcn_mfma_f32_16x16x32_bf16(a, b, c, 0, 0, 0);
}

__device__ inline u16 f2bf(float f) {
    union { float f; unsigned u; } v; v.f = f;
    unsigned r = v.u + 0x7fffu + ((v.u >> 16) & 1u);
    return (u16)(r >> 16);
}

__device__ inline float bf2f(u16 x) {
    union { unsigned u; float f; } v; v.u = ((unsigned)x) << 16; return v.f;
}

// pack two f32 -> two bf16 in one u32
__device__ inline unsigned pk_bf16(float a, float b) {
    union { float f; unsigned u; } x, y; x.f = a; y.f = b;
    return __builtin_amdgcn_perm(y.u + 0x8000u, x.u + 0x8000u, 0x07060302u);
}

__device__ inline void load_lds16(const void* g, void* l) {
    __builtin_amdgcn_global_load_lds(
        (const __attribute__((address_space(1))) void*)g,
        (__attribute__((address_space(3))) void*)l, 16, 0, 0);
}

// ---------------------------------------------------------------------------
// Fused: bf16 casts (text, Wq, Wk, Wo) + per-row sum-of-squares of features.
// Grid: 7168 cast blocks + 2048 rowss blocks (4 rows/block, wave-per-row).
__global__ __launch_bounds__(256) void cast_rows_kernel(const float* __restrict__ text,
                                                        const float* __restrict__ Wq,
                                                        const float* __restrict__ Wk,
                                                        const float* __restrict__ Wo,
                                                        const float* __restrict__ features,
                                                        u16* __restrict__ otext, u16* __restrict__ oWq,
                                                        u16* __restrict__ oWk, u16* __restrict__ oWo,
                                                        float* __restrict__ ssbuf) {
    int blk = blockIdx.x, tid = threadIdx.x;
    if (blk < 7168) {
        int i = blk * 256 + tid;
        const float* src; u16* dst; int off;
        if (i < 1048576)      { src = text; dst = otext; off = i; }
        else if (i < 1310720) { src = Wq;   dst = oWq;   off = i - 1048576; }
        else if (i < 1572864) { src = Wk;   dst = oWk;   off = i - 1310720; }
        else                  { src = Wo;   dst = oWo;   off = i - 1572864; }
        float4 v = ((const float4*)src)[off];
        uint2 p; p.x = pk_bf16(v.x, v.y); p.y = pk_bf16(v.z, v.w);
        ((uint2*)dst)[off] = p;
    } else {
        int row = (blk - 7168) * 4 + (tid >> 6);
        int lane = tid & 63;
        const float4* rp = (const float4*)(features + (size_t)row * 1024) + lane * 4;
        float ss = 0.0f;
        #pragma unroll
        for (int i = 0; i < 4; ++i) {
            float4 v = rp[i];
            ss += v.x * v.x + v.y * v.y + v.z * v.z + v.w * v.w;
        }
        #pragma unroll
        for (int m = 1; m < 64; m <<= 1) ss += __shfl_xor(ss, m, 64);
        if (lane == 0) ssbuf[row] = ss;
    }
}

// ---------------------------------------------------------------------------
// normT: normalize features (using precomputed ss) -> feats_bf (row-major)
// AND Vt (transposed) via one 64x64 LDS tile. Grid (16 n-tiles, 16 d-tiles, 8 b).
__global__ __launch_bounds__(256) void normT_kernel(const float* __restrict__ features,
                                                    const float* __restrict__ ssbuf,
                                                    const float* __restrict__ g,
                                                    u16* __restrict__ feats_bf,
                                                    u16* __restrict__ Vt) {
    __shared__ __align__(16) u16 tile[64][72];
    int tid = threadIdx.x, b = blockIdx.z;
    int n0 = blockIdx.x * 64, d0 = blockIdx.y * 64;
    int r = tid >> 2, cs = (tid & 3) * 16;
    int grow = b * 1024 + n0 + r;

    float rs = rsqrtf(ssbuf[grow] * (1.0f / 1024.0f) + 1e-6f);
    const float4* src = (const float4*)(features + (size_t)grow * 1024 + d0 + cs);
    const float4* gp  = (const float4*)(g + d0 + cs);
    union { u16 s[16]; uint4 v[2]; } ob;
    #pragma unroll
    for (int i = 0; i < 4; ++i) {
        float4 v = src[i], gv = gp[i];
        unsigned lo = pk_bf16(v.x * rs * gv.x, v.y * rs * gv.y);
        unsigned hi = pk_bf16(v.z * rs * gv.z, v.w * rs * gv.w);
        ((unsigned*)ob.s)[i * 2]     = lo;
        ((unsigned*)ob.s)[i * 2 + 1] = hi;
    }
    // row-major output
    uint4* dst = (uint4*)(feats_bf + (size_t)grow * 1024 + d0 + cs);
    dst[0] = ob.v[0]; dst[1] = ob.v[1];
    // transposed via LDS
    #pragma unroll
    for (int i = 0; i < 16; ++i) tile[r][cs + i] = ob.s[i];
    __syncthreads();
    union { u16 s[8]; uint4 v; } t0, t1;
    #pragma unroll
    for (int i = 0; i < 8; ++i) { t0.s[i] = tile[cs + i][r]; t1.s[i] = tile[cs + 8 + i][r]; }
    u16* tdst = Vt + ((size_t)(b * 1024 + d0 + r)) * 1024 + n0 + cs;
    *(uint4*)tdst = t0.v;
    *(uint4*)(tdst + 8) = t1.v;
}

// ---------------------------------------------------------------------------
// Wave-per-row in-place RMSNorm on bf16: rows 0..4095 = Q (g_q, qscale),
// 4096..12287 = K (g_k). No LDS, no barriers. 4 rows per block.
__global__ __launch_bounds__(256) void rmsnorm_qk_kernel(u16* __restrict__ QK,
                                                         const float* __restrict__ g_q,
                                                         const float* __restrict__ g_k,
                                                         float qscale) {
    int tid = threadIdx.x;
    int row = blockIdx.x * 4 + (tid >> 6);
    int lane = tid & 63;
    const float* g = (row < 4096) ? g_q : g_k;
    float outsc = (row < 4096) ? qscale : 1.0f;

    u16* rp = QK + (size_t)row * 1024 + lane * 16;
    union { u16 s[16]; uint4 v[2]; } in;
    in.v[0] = *(const uint4*)rp;
    in.v[1] = *(const uint4*)(rp + 8);
    float x[16], ss = 0.0f;
    #pragma unroll
    for (int i = 0; i < 16; ++i) { x[i] = bf2f(in.s[i]); ss += x[i] * x[i]; }
    #pragma unroll
    for (int m = 1; m < 64; m <<= 1) ss += __shfl_xor(ss, m, 64);
    float rs = rsqrtf(ss * (1.0f / 1024.0f) + 1e-6f) * outsc;
    const float4* gp = (const float4*)(g + lane * 16);
    union { unsigned u[8]; uint4 v[2]; } ob;
    #pragma unroll
    for (int i = 0; i < 4; ++i) {
        float4 gv = gp[i];
        ob.u[i * 2]     = pk_bf16(x[i * 4 + 0] * rs * gv.x, x[i * 4 + 1] * rs * gv.y);
        ob.u[i * 2 + 1] = pk_bf16(x[i * 4 + 2] * rs * gv.z, x[i * 4 + 3] * rs * gv.w);
    }
    *(uint4*)rp = ob.v[0];
    *(uint4*)(rp + 8) = ob.v[1];
}

// ---------------------------------------------------------------------------
// 128x64-tile GEMM, BK=64. LDS split by k-half: As2[2][128][32], Bs2[2][64][32]
// (64B row stride = proven v4/m97 pattern). 24KB LDS -> 6 blocks/CU. 16 k-iters
// of 16 MFMA/wave between barriers (half of v4's drain count).
template <bool BF16OUT>
__device__ __forceinline__ void gemm64_bk64(const u16* __restrict__ A, const u16* __restrict__ B,
                                            const float* __restrict__ bias, void* __restrict__ Cout,
                                            int m_blk, int n_blk, int K, int N,
                                            u16* As, u16* Bs) {
    int tid = threadIdx.x, wave = tid >> 6, lane = tid & 63;
    int quad = lane >> 4, l15 = lane & 15;
    int wm = wave & 1, wn = wave >> 1;
    int arow = tid >> 2, ac = (tid & 3) * 8;   // staging decomposition (64 rows x 4 chunks)

    f32x4 acc[4][2] = {};

    for (int k0 = 0; k0 < K; k0 += 64) {
        // A: 4 issues = (kh, rh); dest As + kh*4096 + rh*2048 + tid*8 (contiguous)
        #pragma unroll
        for (int kh = 0; kh < 2; ++kh)
            #pragma unroll
            for (int rh = 0; rh < 2; ++rh)
                load_lds16(A + (size_t)(m_blk + rh * 64 + arow) * K + k0 + kh * 32 + ac,
                           As + kh * 4096 + rh * 2048 + (wave * 64) * 8);
        // B: 2 issues = (kh); dest Bs + kh*2048 + tid*8
        #pragma unroll
        for (int kh = 0; kh < 2; ++kh)
            load_lds16(B + (size_t)(n_blk + arow) * K + k0 + kh * 32 + ac,
                       Bs + kh * 2048 + (wave * 64) * 8);
        __syncthreads();
        #pragma unroll
        for (int kh = 0; kh < 2; ++kh) {
            bf16x8 af[4], bfr[2];
            #pragma unroll
            for (int t = 0; t < 4; ++t)
                af[t] = *(const bf16x8*)&As[kh * 4096 + (wm * 64 + t * 16 + l15) * 32 + quad * 8];
            #pragma unroll
            for (int t = 0; t < 2; ++t)
                bfr[t] = *(const bf16x8*)&Bs[kh * 2048 + (wn * 32 + t * 16 + l15) * 32 + quad * 8];
            #pragma unroll
            for (int mt = 0; mt < 4; ++mt)
                #pragma unroll
                for (int nt = 0; nt < 2; ++nt)
                    acc[mt][nt] = mfma16(af[mt], bfr[nt], acc[mt][nt]);
        }
        __syncthreads();
    }
    #pragma unroll
    for (int nt = 0; nt < 2; ++nt) {
        int col = n_blk + wn * 32 + nt * 16 + l15;
        float bv = bias[col];
        #pragma unroll
        for (int mt = 0; mt < 4; ++mt) {
            int row0 = m_blk + wm * 64 + mt * 16 + quad * 4;
            #pragma unroll
            for (int r = 0; r < 4; ++r) {
                float val = acc[mt][nt][r] + bv;
                if (BF16OUT) ((u16*)Cout)[(size_t)(row0 + r) * N + col] = f2bf(val);
                else       ((float*)Cout)[(size_t)(row0 + r) * N + col] = val;
            }
        }
    }
}

// merged Q-proj (512 blocks) + K-proj (1024 blocks), bf16 out
__global__ __launch_bounds__(256) void gemm_qk_kernel(const u16* __restrict__ text_bf,
                                                      const u16* __restrict__ Wq,
                                                      const u16* __restrict__ feats_bf,
                                                      const u16* __restrict__ Wk,
                                                      const float* __restrict__ b_q,
                                                      const float* __restrict__ b_k,
                                                      u16* __restrict__ QK) {
    __shared__ __align__(16) u16 As[2 * 128 * 32];
    __shared__ __align__(16) u16 Bs[2 * 64 * 32];
    int id = blockIdx.x;
    if (id < 512) {
        gemm64_bk64<true>(text_bf, Wq, b_q, QK, (id & 31) * 128, (id >> 5) * 64, 1024, 1024, As, Bs);
    } else {
        id -= 512;
        gemm64_bk64<true>(feats_bf, Wk, b_k, QK + 4096 * 1024,
                          (id & 63) * 128, (id >> 6) * 64, 1024, 1024, As, Bs);
    }
}

// O-projection, fp32 out (512 blocks)
__global__ __launch_bounds__(256) void gemm_o_kernel(const u16* __restrict__ A,
                                                     const u16* __restrict__ B,
                                                     const float* __restrict__ bias,
                                                     float* __restrict__ C) {
    __shared__ __align__(16) u16 As[2 * 128 * 32];
    __shared__ __align__(16) u16 Bs[2 * 64 * 32];
    int id = blockIdx.x;
    gemm64_bk64<false>(A, B, bias, C, (id & 31) * 128, (id >> 5) * 64, 1024, 1024, As, Bs);
}

// ---------------------------------------------------------------------------
// Flash attention (v4 structure, unchanged): n-chunk 64, 25.6KB LDS, fixed-max
// exp2 softmax, S^T/O^T MFMA orientation, XOR-swizzled K/V staging.
__global__ __launch_bounds__(256) void attn_kernel(const u16* __restrict__ Q,
                                                   const u16* __restrict__ K,
                                                   const u16* __restrict__ Vt,
                                                   u16* __restrict__ Out) {
    int bh = blockIdx.x, qt = blockIdx.y;
    int b = bh >> 4, h = bh & 15;
    int tid = threadIdx.x, wave = tid >> 6, lane = tid & 63;
    int quad = lane >> 4, l15 = lane & 15;

    __shared__ __align__(16) u16 Ks[64 * 64];
    __shared__ __align__(16) u16 Vs[64 * 64];
    __shared__ __align__(16) u16 Plds[4][16 * 72];
    u16* Pw = &Plds[wave][0];

    const size_t qoff = ((size_t)(b * 512 + qt * 64 + wave * 16 + l15)) * 1024 + h * 64 + quad * 8;
    bf16x8 qf0 = *(const bf16x8*)(Q + qoff);
    bf16x8 qf1 = *(const bf16x8*)(Q + qoff + 32);

    int srl = lane >> 3, scl = lane & 7;
    const u16* Kbase = K + ((size_t)(b * 1024)) * 1024 + h * 64;
    const u16* Vbase = Vt + ((size_t)(b * 1024 + h * 64)) * 1024;

    __bf16 onev = (__bf16)1.0f;
    bf16x8 ones = {onev, onev, onev, onev, onev, onev, onev, onev};

    f32x4 o[4] = {};
    f32x4 lac = {0.0f, 0.0f, 0.0f, 0.0f};

    for (int n0 = 0; n0 < 1024; n0 += 64) {
        #pragma unroll
        for (int j = 0; j < 2; ++j) {
            int row = wave * 16 + j * 8 + srl;
            load_lds16(Kbase + (size_t)(n0 + row) * 1024 + (scl ^ srl) * 8,
                       Ks + (wave * 16 + j * 8) * 64);
            load_lds16(Vbase + (size_t)row * 1024 + n0 + (scl ^ srl) * 8,
                       Vs + (wave * 16 + j * 8) * 64);
        }
        __syncthreads();

        f32x4 s[4];
        #pragma unroll
        for (int nt = 0; nt < 4; ++nt) {
            int R = nt * 16 + l15;
            int c1 = (quad ^ (l15 & 7)) * 8;
            bf16x8 kf0 = *(const bf16x8*)&Ks[R * 64 + c1];
            bf16x8 kf1 = *(const bf16x8*)&Ks[R * 64 + (c1 ^ 32)];
            f32x4 z = {-16.0f, -16.0f, -16.0f, -16.0f};
            s[nt] = mfma16(kf0, qf0, z);
            s[nt] = mfma16(kf1, qf1, s[nt]);
        }

        #pragma unroll
        for (int nt = 0; nt < 4; ++nt) {
            uint2 pk;
            pk.x = pk_bf16(exp2f(s[nt][0]), exp2f(s[nt][1]));
            pk.y = pk_bf16(exp2f(s[nt][2]), exp2f(s[nt][3]));
            *(uint2*)&Pw[l15 * 72 + nt * 16 + quad * 4] = pk;
        }

        bf16x8 pf[2];
        #pragma unroll
        for (int kc = 0; kc < 2; ++kc)
            pf[kc] = *(const bf16x8*)&Pw[l15 * 72 + kc * 32 + quad * 8];
        #pragma unroll
        for (int kc = 0; kc < 2; ++kc) {
            lac = mfma16(ones, pf[kc], lac);
            #pragma unroll
            for (int dt = 0; dt < 4; ++dt) {
                int d = dt * 16 + l15;
                int ch = ((kc * 4 + quad) ^ (l15 & 7)) * 8;
                bf16x8 vf = *(const bf16x8*)&Vs[d * 64 + ch];
                o[dt] = mfma16(vf, pf[kc], o[dt]);
            }
        }
        __syncthreads();
    }

    float il = 1.0f / lac[0];
    size_t obase = ((size_t)(b * 512 + qt * 64 + wave * 16 + l15)) * 1024 + h * 64 + quad * 4;
    #pragma unroll
    for (int dt = 0; dt < 4; ++dt) {
        uint2 pk;
        pk.x = pk_bf16(o[dt][0] * il, o[dt][1] * il);
        pk.y = pk_bf16(o[dt][2] * il, o[dt][3] * il);
        *(uint2*)(Out + obase + dt * 16) = pk;
    }
}

// ---------------------------------------------------------------------------
extern "C" void kernel_launch(void* const* d_in, const int* in_sizes, int n_in,
                              void* d_out, int out_size, void* d_ws, size_t ws_size,
                              hipStream_t stream) {
    const float* text     = (const float*)d_in[0];
    const float* features = (const float*)d_in[1];
    const float* W_q      = (const float*)d_in[2];
    const float* b_q      = (const float*)d_in[3];
    const float* W_k      = (const float*)d_in[4];
    const float* b_k      = (const float*)d_in[5];
    const float* W_o      = (const float*)d_in[6];
    const float* b_o      = (const float*)d_in[7];
    const float* g_feat   = (const float*)d_in[8];
    const float* g_q      = (const float*)d_in[9];
    const float* g_k      = (const float*)d_in[10];

    char* ws = (char*)d_ws;
    u16*   text_bf  = (u16*)(ws + 0);            //  8 MB [4096,1024]
    u16*   Wq_bf    = (u16*)(ws + 8388608);      //  2 MB
    u16*   Wk_bf    = (u16*)(ws + 10485760);     //  2 MB
    u16*   Wo_bf    = (u16*)(ws + 12582912);     //  2 MB
    u16*   feats_bf = (u16*)(ws + 14680064);     // 16 MB [8192,1024]
    u16*   Vt       = (u16*)(ws + 31457280);     // 16 MB [8][1024 d][1024 n]
    u16*   QKbuf    = (u16*)(ws + 48234496);     // 24 MB [12288,1024] (Q, then K)
    u16*   attn_bf  = (u16*)(ws + 73400320);     //  8 MB [4096,1024]
    float* ssbuf    = (float*)(ws + 81788928);   // 32 KB [8192]

    const float QSCALE = 0.18033688011112042f;   // 0.125 * log2(e)

    // 1) casts + feature row sum-squares
    cast_rows_kernel<<<9216, 256, 0, stream>>>(text, W_q, W_k, W_o, features,
                                               text_bf, Wq_bf, Wk_bf, Wo_bf, ssbuf);
    // 2) normalize features -> feats_bf and Vt (transposed) in one pass
    normT_kernel<<<dim3(16, 16, 8), 256, 0, stream>>>(features, ssbuf, g_feat, feats_bf, Vt);
    // 3) Q-proj + K-proj (raw, bf16)
    gemm_qk_kernel<<<1536, 256, 0, stream>>>(text_bf, Wq_bf, feats_bf, Wk_bf, b_q, b_k, QKbuf);
    // 4) in-place RMSNorm of Q (with attn scale folded) and K
    rmsnorm_qk_kernel<<<3072, 256, 0, stream>>>(QKbuf, g_q, g_k, QSCALE);
    // 5) fused attention
    attn_kernel<<<dim3(128, 8), 256, 0, stream>>>(QKbuf, QKbuf + 4096 * 1024, Vt, attn_bf);
    // 6) O-projection -> fp32 d_out
    gemm_o_kernel<<<512, 256, 0, stream>>>(attn_bf, Wo_bf, b_o, (float*)d_out);
}